// Round 3
// baseline (7680.746 us; speedup 1.0000x reference)
//
#include <hip/hip_runtime.h>
#include <math.h>

#define Hh 240
#define Ww 480
#define HW 115200      // Hh*Ww
#define Cc 128
#define Kk 1152        // Cc*9
#define HALFW 240      // Ww/2
#define NB_RED 1440

typedef unsigned int u32;
typedef __attribute__((address_space(3))) u32 lds_u32;
typedef const __attribute__((address_space(1))) u32 glb_u32;

// ---------------------------------------------------------------------------
// geo_pad-fused index: flat index into a [C][H][W] plane for padded coords
// (r in [-1,Hh], c in [-1,Ww]).
// ---------------------------------------------------------------------------
__device__ __forceinline__ int geo_index(int ch, int r, int c) {
    int wv = (c < 0) ? (Ww - 1) : ((c >= Ww) ? 0 : c);
    int rr;
    if (r < 0)        { rr = 0;      wv = (wv >= HALFW) ? wv - HALFW : wv + HALFW; }
    else if (r >= Hh) { rr = Hh - 1; wv = (wv >= HALFW) ? wv - HALFW : wv + HALFW; }
    else              { rr = r; }
    return (ch * Hh + rr) * Ww + wv;
}

__device__ __forceinline__ float padfetch(const float* __restrict__ p, int yi, int xj) {
    int r = yi - 1, c = xj - 1;
    int wv = (c < 0) ? (Ww - 1) : ((c >= Ww) ? 0 : c);
    int rr;
    if (r < 0)        { rr = 0;      wv = (wv >= HALFW) ? wv - HALFW : wv + HALFW; }
    else if (r >= Hh) { rr = Hh - 1; wv = (wv >= HALFW) ? wv - HALFW : wv + HALFW; }
    else              { rr = r; }
    return p[rr * Ww + wv];
}

// small-angle double sincos (|x| <~ 0.7), libm fallback — IDENTICAL to round 2
__device__ __forceinline__ void sincos_small(double x, double* s, double* c) {
    double x2 = x * x;
    if (x2 > 0.49) { *s = sin(x); *c = cos(x); return; }
    *s = x * (1.0 + x2 * (-1.6666666666666666e-1 + x2 * (8.3333333333333333e-3 +
         x2 * (-1.9841269841269841e-4 + x2 * (2.7557319223985893e-6 - x2 * 2.5052108385441720e-8)))));
    *c = 1.0 + x2 * (-0.5 + x2 * (4.1666666666666666e-2 + x2 * (-1.3888888888888889e-3 +
         x2 * (2.4801587301587302e-5 - x2 * 2.7557319223985893e-7))));
}

// ---------------------------------------------------------------------------
__global__ void transpose_w(const float* __restrict__ w, float* __restrict__ wT, int N) {
    int idx = blockIdx.x * 256 + threadIdx.x;      // idx = k*N + n
    if (idx >= N * Kk) return;
    int k = idx / N;
    int n = idx - k * N;
    wT[idx] = w[n * Kk + k];
}

// ---------------------------------------------------------------------------
// implicit-GEMM 3x3 conv, geo_pad fused into the gather.
// 128x128 tile, BK=32, 256 threads, 8x8 micro-tile.
// A: global_load_lds direct-to-LDS (double-buffered). B: direct from global
// (L1-resident weight slab). FMA order identical to round 2 (bit-exact).
// ---------------------------------------------------------------------------
__global__ __launch_bounds__(256)
void conv_gemm(const float* __restrict__ in,    // [Cc][HW] batch plane base
               const float* __restrict__ wT,    // [Kk][N]
               const float* __restrict__ bias,  // [N]
               float* __restrict__ out,         // [N][HW]
               int N)
{
    const int tid = threadIdx.x;
    const int tx = tid & 15;     // m
    const int ty = tid >> 4;     // n
    const int m0 = blockIdx.x * 128;
    const int n0 = blockIdx.y * 128;

    __shared__ float As[2][32][128];  // double-buffered A tile [k][m]

    // fixed staging identity: this thread always stages column mi = tid&127,
    // rows ki = (tid>>7) + 2*i. Wave-uniform LDS dst base: row + (tid&64).
    const int mi      = tid & 127;
    const int ki0     = tid >> 7;
    const int colbase = tid & 64;            // wave-uniform
    const int m       = m0 + mi;
    const int h       = m / Ww;
    const int w       = m - h * Ww;
    (void)mi;

    float acc[8][8] = {};

    auto stage = [&](int buf, int kt) {
        #pragma unroll
        for (int i = 0; i < 16; i++) {
            int k  = kt + ki0 + 2 * i;
            int ic = k / 9;
            int t9 = k - ic * 9;
            int kh = t9 / 3;
            int kw = t9 - kh * 3;
            int gidx = geo_index(ic, h + kh - 1, w + kw - 1);
            __builtin_amdgcn_global_load_lds(
                (glb_u32*)(in + gidx),
                (lds_u32*)&As[buf][ki0 + 2 * i][colbase],
                4, 0, 0);
        }
    };

    stage(0, 0);
    __syncthreads();

    const float* wTb = wT + n0;
    int buf = 0;
    for (int kt = 0; kt < Kk; kt += 32) {
        if (kt + 32 < Kk) stage(buf ^ 1, kt + 32);
        const float* wTk = wTb + (size_t)kt * N;
        #pragma unroll
        for (int kk = 0; kk < 32; kk++) {
            float4 b0 = *(const float4*)&wTk[kk * N + ty * 4];
            float4 b1 = *(const float4*)&wTk[kk * N + 64 + ty * 4];
            float4 a0 = *(const float4*)&As[buf][kk][tx * 4];
            float4 a1 = *(const float4*)&As[buf][kk][64 + tx * 4];
            float av[8] = {a0.x, a0.y, a0.z, a0.w, a1.x, a1.y, a1.z, a1.w};
            float bv[8] = {b0.x, b0.y, b0.z, b0.w, b1.x, b1.y, b1.z, b1.w};
            #pragma unroll
            for (int i = 0; i < 8; i++)
                #pragma unroll
                for (int j = 0; j < 8; j++)
                    acc[i][j] = fmaf(av[i], bv[j], acc[i][j]);
        }
        __syncthreads();
        buf ^= 1;
    }

    #pragma unroll
    for (int hn = 0; hn < 2; hn++)
        #pragma unroll
        for (int j = 0; j < 4; j++) {
            int n = n0 + hn * 64 + ty * 4 + j;
            float bv = bias[n];
            #pragma unroll
            for (int hm = 0; hm < 2; hm++) {
                float4 o;
                o.x = acc[hm * 4 + 0][hn * 4 + j] + bv;
                o.y = acc[hm * 4 + 1][hn * 4 + j] + bv;
                o.z = acc[hm * 4 + 2][hn * 4 + j] + bv;
                o.w = acc[hm * 4 + 3][hn * 4 + j] + bv;
                *(float4*)&out[(size_t)n * HW + m0 + hm * 64 + tx * 4] = o;
            }
        }
}

// ---------------------------------------------------------------------------
// deterministic two-stage LayerNorm stats
// ---------------------------------------------------------------------------
__global__ __launch_bounds__(256)
void reduce_stats(const float* __restrict__ y, float* __restrict__ part) {
    const int n4 = (Cc * HW) / 4;
    float s = 0.f, ss = 0.f;
    for (int i = blockIdx.x * 256 + threadIdx.x; i < n4; i += NB_RED * 256) {
        float4 v = ((const float4*)y)[i];
        s  += v.x + v.y + v.z + v.w;
        ss += v.x * v.x + v.y * v.y + v.z * v.z + v.w * v.w;
    }
    #pragma unroll
    for (int o = 32; o > 0; o >>= 1) { s += __shfl_down(s, o); ss += __shfl_down(ss, o); }
    __shared__ float ls[4], lss[4];
    int wid = threadIdx.x >> 6, lane = threadIdx.x & 63;
    if (lane == 0) { ls[wid] = s; lss[wid] = ss; }
    __syncthreads();
    if (threadIdx.x == 0) {
        part[blockIdx.x * 2]     = ls[0] + ls[1] + ls[2] + ls[3];
        part[blockIdx.x * 2 + 1] = lss[0] + lss[1] + lss[2] + lss[3];
    }
}

__global__ __launch_bounds__(256)
void finalize_stats(const float* __restrict__ part, float* __restrict__ stats) {
    float s = 0.f, ss = 0.f;
    for (int i = threadIdx.x; i < NB_RED; i += 256) { s += part[2 * i]; ss += part[2 * i + 1]; }
    #pragma unroll
    for (int o = 32; o > 0; o >>= 1) { s += __shfl_down(s, o); ss += __shfl_down(ss, o); }
    __shared__ float ls[4], lss[4];
    int wid = threadIdx.x >> 6, lane = threadIdx.x & 63;
    if (lane == 0) { ls[wid] = s; lss[wid] = ss; }
    __syncthreads();
    if (threadIdx.x == 0) {
        stats[0] = ls[0] + ls[1] + ls[2] + ls[3];
        stats[1] = lss[0] + lss[1] + lss[2] + lss[3];
    }
}

__global__ void norm_silu(float* __restrict__ y, const float* __restrict__ g,
                          const float* __restrict__ bb, const float* __restrict__ stats) {
    int i = blockIdx.x * 256 + threadIdx.x;
    if (i >= Cc * HW) return;
    const float invN = 1.f / (float)(Cc * HW);
    float mu  = stats[0] * invN;
    float var = stats[1] * invN - mu * mu;
    float inv = rsqrtf(var + 1e-5f);
    float z = (y[i] - mu) * inv * g[i] + bb[i];
    y[i] = z / (1.f + expf(-z));
}

// ---------------------------------------------------------------------------
__global__ void pix_trig(const float* __restrict__ latg, double* __restrict__ sphid) {
    int m = blockIdx.x * 256 + threadIdx.x;
    if (m >= HW) return;
    double phi = (double)latg[m];
    sphid[m]      = sin(phi);
    sphid[HW + m] = cos(phi);
}

// ---------------------------------------------------------------------------
// departure-point trig + bicubic sample. Hybrid precision: fp32 fast path for
// low-amplification pixels; bit-identical-to-round-2 fp64 path otherwise.
// ---------------------------------------------------------------------------
__global__ __launch_bounds__(256)
void semilag(const float* __restrict__ vel,     // [2*Cc][HW] batch base
             const float* __restrict__ hid,     // [Cc][HW] batch base
             const double* __restrict__ sphid,  // [2][HW] sin/cos(lat)
             const float* __restrict__ lng,     // [HW]
             const float* __restrict__ dtp,
             float* __restrict__ out)           // [Cc][HW] batch base
{
    int idx = blockIdx.x * 256 + threadIdx.x;
    if (idx >= Cc * HW) return;
    int c = idx / HW;
    int m = idx - c * HW;

    const double TWO_PI = 6.2831853071795864769252867665590;
    const double PI_D   = 3.1415926535897932384626433832795;
    const float  PI2F   = 6.28318530717958647692f;

    float uf = vel[idx];
    float vf = vel[Cc * HW + idx];
    float dtf = dtp[0];
    double sphi_d = sphid[m], cphi_d = sphid[HW + m];
    float lam_f = lng[m];

    // ---- fp32 gate evaluation ----
    float lonp_f = -uf * dtf, latp_f = -vf * dtf;
    float slp_f = sinf(latp_f), clp_f = cosf(latp_f);
    float slo_f = sinf(lonp_f), clo_f = cosf(lonp_f);
    float sphi_f = (float)sphi_d, cphi_f = (float)cphi_d;
    float sinlat_f = slp_f * cphi_f + clp_f * clo_f * sphi_f;
    float num_f = clp_f * slo_f;
    float den_f = clp_f * clo_f * cphi_f - slp_f * sphi_f;
    float r2_f  = num_f * num_f + den_f * den_f;

    float lon_w = lam_f + atan2f(num_f, den_f) + PI2F;
    lon_w = lon_w - floorf(lon_w / PI2F) * PI2F;
    float seam = fminf(lon_w, PI2F - lon_w);

    bool fast = (cphi_f > 0.2f) & (r2_f > 0.01f) & (fabsf(sinlat_f) < 0.98f) & (seam > 1e-4f);

    double ixd, iyd;
    if (fast) {
        float sl = fminf(fmaxf(sinlat_f, -1.f + 1e-7f), 1.f - 1e-7f);
        float lat_dep = asinf(sl);
        float gx = (lon_w / PI2F * 2.f - 1.f) * (480.f / 482.f);
        float gy = (lat_dep / 3.14159265358979323846f * 2.f - 1.f) * (240.f / 242.f);
        ixd = (double)fminf(fmaxf((gx + 1.f) * 0.5f * 481.f, 0.f), 481.f);
        iyd = (double)fminf(fmaxf((gy + 1.f) * 0.5f * 241.f, 0.f), 241.f);
    } else {
        // ---- fp64 path: IDENTICAL arithmetic to round 2 ----
        double dt = (double)dtf;
        double u = (double)uf;
        double v = (double)vf;
        double lonp = -u * dt, latp = -v * dt;
        double slp, clp, slo, clo;
        sincos_small(latp, &slp, &clp);
        sincos_small(lonp, &slo, &clo);
        double sphi = sphi_d, cphi = cphi_d;

        double sinlat = slp * cphi + clp * clo * sphi;
        sinlat = fmin(fmax(sinlat, -1.0 + 1e-7), 1.0 - 1e-7);
        double lat_dep = asin(sinlat);

        double num = clp * slo;
        double den = clp * clo * cphi - slp * sphi;
        double lon_dep = (double)lam_f + atan2(num, den);
        double xr = lon_dep + TWO_PI;
        xr = xr - floor(xr / TWO_PI) * TWO_PI;

        double gx = (xr / TWO_PI * 2.0 - 1.0) * (480.0 / 482.0);
        double gy = (lat_dep / PI_D * 2.0 - 1.0) * (240.0 / 242.0);

        ixd = fmin(fmax((gx + 1.0) * 0.5 * 481.0, 0.0), 481.0);
        iyd = fmin(fmax((gy + 1.0) * 0.5 * 241.0, 0.0), 241.0);
    }

    double x0d = floor(ixd), y0d = floor(iyd);
    float fx = (float)(ixd - x0d), fy = (float)(iyd - y0d);
    int x0 = (int)x0d, y0 = (int)y0d;

    const float a = -0.75f;
    float wx[4], wy[4];
    {
        float t = fx;
        float t1 = 1.f + t, t2 = 2.f - t, s1 = 1.f - t;
        wx[0] = ((a * t1 - 5.f * a) * t1 + 8.f * a) * t1 - 4.f * a;
        wx[1] = ((a + 2.f) * t - (a + 3.f)) * t * t + 1.f;
        wx[2] = ((a + 2.f) * s1 - (a + 3.f)) * s1 * s1 + 1.f;
        wx[3] = ((a * t2 - 5.f * a) * t2 + 8.f * a) * t2 - 4.f * a;
        t = fy;
        t1 = 1.f + t; t2 = 2.f - t; s1 = 1.f - t;
        wy[0] = ((a * t1 - 5.f * a) * t1 + 8.f * a) * t1 - 4.f * a;
        wy[1] = ((a + 2.f) * t - (a + 3.f)) * t * t + 1.f;
        wy[2] = ((a + 2.f) * s1 - (a + 3.f)) * s1 * s1 + 1.f;
        wy[3] = ((a * t2 - 5.f * a) * t2 + 8.f * a) * t2 - 4.f * a;
    }

    const float* plane = hid + (size_t)c * HW;
    float accv = 0.f;
    #pragma unroll
    for (int i = 0; i < 4; i++) {
        int yi = min(max(y0 + i - 1, 0), 241);
        float row = 0.f;
        #pragma unroll
        for (int j = 0; j < 4; j++) {
            int xj = min(max(x0 + j - 1, 0), 481);
            row = fmaf(wx[j], padfetch(plane, yi, xj), row);
        }
        accv = fmaf(wy[i], row, accv);
    }
    out[idx] = accv;
}

// ---------------------------------------------------------------------------
extern "C" void kernel_launch(void* const* d_in, const int* in_sizes, int n_in,
                              void* d_out, int out_size, void* d_ws, size_t ws_size,
                              hipStream_t stream)
{
    const float* hidden = (const float*)d_in[0];
    const float* latg   = (const float*)d_in[1];
    const float* lng    = (const float*)d_in[2];
    const float* w1     = (const float*)d_in[3];
    const float* b1     = (const float*)d_in[4];
    const float* g      = (const float*)d_in[5];
    const float* lb     = (const float*)d_in[6];
    const float* w2     = (const float*)d_in[7];
    const float* b2     = (const float*)d_in[8];
    const float* dt     = (const float*)d_in[9];
    float* out = (float*)d_out;

    // ws layout (floats): stats[4] | part[2880] | wT1 | wT2 | y1[C*HW] | vel[2C*HW]
    float* ws    = (float*)d_ws;
    float* stats = ws;
    float* part  = ws + 4;
    float* wT1   = part + 2 * NB_RED;
    float* wT2   = wT1 + Kk * Cc;
    float* y1    = wT2 + Kk * 2 * Cc;
    float* vel   = y1 + (size_t)Cc * HW;
    double* dbuf = (double*)y1;   // y1 region reused after conv2 (8B-aligned)

    transpose_w<<<(Cc * Kk + 255) / 256, 256, 0, stream>>>(w1, wT1, Cc);
    transpose_w<<<(2 * Cc * Kk + 255) / 256, 256, 0, stream>>>(w2, wT2, 2 * Cc);

    for (int b = 0; b < 2; b++) {
        const float* hb = hidden + (size_t)b * Cc * HW;
        conv_gemm<<<dim3(HW / 128, 1), 256, 0, stream>>>(hb, wT1, b1, y1, Cc);
        reduce_stats<<<NB_RED, 256, 0, stream>>>(y1, part);
        finalize_stats<<<1, 256, 0, stream>>>(part, stats + 2 * b);
        norm_silu<<<(Cc * HW) / 256, 256, 0, stream>>>(y1, g, lb, stats + 2 * b);
        conv_gemm<<<dim3(HW / 128, 2), 256, 0, stream>>>(y1, wT2, b2, vel, 2 * Cc);
        pix_trig<<<(HW + 255) / 256, 256, 0, stream>>>(latg + (size_t)b * HW, dbuf);
        semilag<<<(Cc * HW) / 256, 256, 0, stream>>>(vel, hb, dbuf,
                                                     lng + (size_t)b * HW, dt,
                                                     out + (size_t)b * Cc * HW);
    }
}

// Round 4
// 5570.841 us; speedup vs baseline: 1.3787x; 1.3787x over previous
//
#include <hip/hip_runtime.h>
#include <math.h>

#define Hh 240
#define Ww 480
#define HW 115200      // Hh*Ww
#define Cc 128
#define Kk 1152        // Cc*9
#define HALFW 240      // Ww/2
#define NB_RED 1440

typedef unsigned int u32;
typedef __attribute__((address_space(3))) u32 lds_u32;
typedef const __attribute__((address_space(1))) u32 glb_u32;

// ---------------------------------------------------------------------------
// geo_pad-fused index: flat index into a [C][H][W] plane for padded coords
// (r in [-1,Hh], c in [-1,Ww]).
// ---------------------------------------------------------------------------
__device__ __forceinline__ int geo_index(int ch, int r, int c) {
    int wv = (c < 0) ? (Ww - 1) : ((c >= Ww) ? 0 : c);
    int rr;
    if (r < 0)        { rr = 0;      wv = (wv >= HALFW) ? wv - HALFW : wv + HALFW; }
    else if (r >= Hh) { rr = Hh - 1; wv = (wv >= HALFW) ? wv - HALFW : wv + HALFW; }
    else              { rr = r; }
    return (ch * Hh + rr) * Ww + wv;
}

__device__ __forceinline__ float padfetch(const float* __restrict__ p, int yi, int xj) {
    int r = yi - 1, c = xj - 1;
    int wv = (c < 0) ? (Ww - 1) : ((c >= Ww) ? 0 : c);
    int rr;
    if (r < 0)        { rr = 0;      wv = (wv >= HALFW) ? wv - HALFW : wv + HALFW; }
    else if (r >= Hh) { rr = Hh - 1; wv = (wv >= HALFW) ? wv - HALFW : wv + HALFW; }
    else              { rr = r; }
    return p[rr * Ww + wv];
}

// small-angle double sincos (|x| <~ 0.7), libm fallback — IDENTICAL to round 2
__device__ __forceinline__ void sincos_small(double x, double* s, double* c) {
    double x2 = x * x;
    if (x2 > 0.49) { *s = sin(x); *c = cos(x); return; }
    *s = x * (1.0 + x2 * (-1.6666666666666666e-1 + x2 * (8.3333333333333333e-3 +
         x2 * (-1.9841269841269841e-4 + x2 * (2.7557319223985893e-6 - x2 * 2.5052108385441720e-8)))));
    *c = 1.0 + x2 * (-0.5 + x2 * (4.1666666666666666e-2 + x2 * (-1.3888888888888889e-3 +
         x2 * (2.4801587301587302e-5 - x2 * 2.7557319223985893e-7))));
}

// ---------------------------------------------------------------------------
__global__ void transpose_w(const float* __restrict__ w, float* __restrict__ wT, int N) {
    int idx = blockIdx.x * 256 + threadIdx.x;      // idx = k*N + n
    if (idx >= N * Kk) return;
    int k = idx / N;
    int n = idx - k * N;
    wT[idx] = w[n * Kk + k];
}

// ---------------------------------------------------------------------------
// implicit-GEMM 3x3 conv, geo_pad fused into the gather.
// 128x128 tile, BK=32, 256 threads, 8x8 micro-tile.
// A AND B staged via global_load_lds, double-buffered; inner loop is pure
// ds_read+FMA. FMA order per output identical to rounds 2/3 (bit-exact).
// ---------------------------------------------------------------------------
__global__ __launch_bounds__(256)
void conv_gemm(const float* __restrict__ in,    // [Cc][HW] batch plane base
               const float* __restrict__ wT,    // [Kk][N]
               const float* __restrict__ bias,  // [N]
               float* __restrict__ out,         // [N][HW]
               int N)
{
    const int tid = threadIdx.x;
    const int tx = tid & 15;     // m
    const int ty = tid >> 4;     // n
    const int m0 = blockIdx.x * 128;
    const int n0 = blockIdx.y * 128;

    __shared__ float As[2][32][128];  // [buf][k][m]
    __shared__ float Bs[2][32][128];  // [buf][k][n]

    // staging identity: this thread stages column (tid&127), rows (tid>>7)+2i.
    // LDS dst = wave-uniform base (row, tid&64) + lane*4 (HW-imposed layout).
    const int ki0     = tid >> 7;
    const int colbase = tid & 64;            // wave-uniform
    const int m       = m0 + (tid & 127);
    const int h       = m / Ww;
    const int w       = m - h * Ww;

    float acc[8][8] = {};

    auto stageA = [&](int buf, int kt) {
        #pragma unroll
        for (int i = 0; i < 16; i++) {
            int k  = kt + ki0 + 2 * i;
            int ic = k / 9;
            int t9 = k - ic * 9;
            int kh = t9 / 3;
            int kw = t9 - kh * 3;
            int gidx = geo_index(ic, h + kh - 1, w + kw - 1);
            __builtin_amdgcn_global_load_lds(
                (glb_u32*)(in + gidx),
                (lds_u32*)&As[buf][ki0 + 2 * i][colbase],
                4, 0, 0);
        }
    };
    auto stageB = [&](int buf, int kt) {
        const float* src = wT + (size_t)(kt + ki0) * N + n0 + (tid & 127);
        #pragma unroll
        for (int i = 0; i < 16; i++) {
            __builtin_amdgcn_global_load_lds(
                (glb_u32*)(src + (size_t)(2 * i) * N),
                (lds_u32*)&Bs[buf][ki0 + 2 * i][colbase],
                4, 0, 0);
        }
    };

    stageA(0, 0);
    stageB(0, 0);
    __syncthreads();

    int buf = 0;
    for (int kt = 0; kt < Kk; kt += 32) {
        if (kt + 32 < Kk) { stageA(buf ^ 1, kt + 32); stageB(buf ^ 1, kt + 32); }
        #pragma unroll
        for (int kk = 0; kk < 32; kk++) {
            float4 a0 = *(const float4*)&As[buf][kk][tx * 4];
            float4 a1 = *(const float4*)&As[buf][kk][64 + tx * 4];
            float4 b0 = *(const float4*)&Bs[buf][kk][ty * 4];
            float4 b1 = *(const float4*)&Bs[buf][kk][64 + ty * 4];
            float av[8] = {a0.x, a0.y, a0.z, a0.w, a1.x, a1.y, a1.z, a1.w};
            float bv[8] = {b0.x, b0.y, b0.z, b0.w, b1.x, b1.y, b1.z, b1.w};
            #pragma unroll
            for (int i = 0; i < 8; i++)
                #pragma unroll
                for (int j = 0; j < 8; j++)
                    acc[i][j] = fmaf(av[i], bv[j], acc[i][j]);
        }
        __syncthreads();
        buf ^= 1;
    }

    #pragma unroll
    for (int hn = 0; hn < 2; hn++)
        #pragma unroll
        for (int j = 0; j < 4; j++) {
            int n = n0 + hn * 64 + ty * 4 + j;
            float bv = bias[n];
            #pragma unroll
            for (int hm = 0; hm < 2; hm++) {
                float4 o;
                o.x = acc[hm * 4 + 0][hn * 4 + j] + bv;
                o.y = acc[hm * 4 + 1][hn * 4 + j] + bv;
                o.z = acc[hm * 4 + 2][hn * 4 + j] + bv;
                o.w = acc[hm * 4 + 3][hn * 4 + j] + bv;
                *(float4*)&out[(size_t)n * HW + m0 + hm * 64 + tx * 4] = o;
            }
        }
}

// ---------------------------------------------------------------------------
// deterministic two-stage LayerNorm stats
// ---------------------------------------------------------------------------
__global__ __launch_bounds__(256)
void reduce_stats(const float* __restrict__ y, float* __restrict__ part) {
    const int n4 = (Cc * HW) / 4;
    float s = 0.f, ss = 0.f;
    for (int i = blockIdx.x * 256 + threadIdx.x; i < n4; i += NB_RED * 256) {
        float4 v = ((const float4*)y)[i];
        s  += v.x + v.y + v.z + v.w;
        ss += v.x * v.x + v.y * v.y + v.z * v.z + v.w * v.w;
    }
    #pragma unroll
    for (int o = 32; o > 0; o >>= 1) { s += __shfl_down(s, o); ss += __shfl_down(ss, o); }
    __shared__ float ls[4], lss[4];
    int wid = threadIdx.x >> 6, lane = threadIdx.x & 63;
    if (lane == 0) { ls[wid] = s; lss[wid] = ss; }
    __syncthreads();
    if (threadIdx.x == 0) {
        part[blockIdx.x * 2]     = ls[0] + ls[1] + ls[2] + ls[3];
        part[blockIdx.x * 2 + 1] = lss[0] + lss[1] + lss[2] + lss[3];
    }
}

__global__ __launch_bounds__(256)
void finalize_stats(const float* __restrict__ part, float* __restrict__ stats) {
    float s = 0.f, ss = 0.f;
    for (int i = threadIdx.x; i < NB_RED; i += 256) { s += part[2 * i]; ss += part[2 * i + 1]; }
    #pragma unroll
    for (int o = 32; o > 0; o >>= 1) { s += __shfl_down(s, o); ss += __shfl_down(ss, o); }
    __shared__ float ls[4], lss[4];
    int wid = threadIdx.x >> 6, lane = threadIdx.x & 63;
    if (lane == 0) { ls[wid] = s; lss[wid] = ss; }
    __syncthreads();
    if (threadIdx.x == 0) {
        stats[0] = ls[0] + ls[1] + ls[2] + ls[3];
        stats[1] = lss[0] + lss[1] + lss[2] + lss[3];
    }
}

__global__ void norm_silu(float* __restrict__ y, const float* __restrict__ g,
                          const float* __restrict__ bb, const float* __restrict__ stats) {
    int i = blockIdx.x * 256 + threadIdx.x;
    if (i >= Cc * HW) return;
    const float invN = 1.f / (float)(Cc * HW);
    float mu  = stats[0] * invN;
    float var = stats[1] * invN - mu * mu;
    float inv = rsqrtf(var + 1e-5f);
    float z = (y[i] - mu) * inv * g[i] + bb[i];
    y[i] = z / (1.f + expf(-z));
}

// ---------------------------------------------------------------------------
__global__ void pix_trig(const float* __restrict__ latg, double* __restrict__ sphid) {
    int m = blockIdx.x * 256 + threadIdx.x;
    if (m >= HW) return;
    double phi = (double)latg[m];
    sphid[m]      = sin(phi);
    sphid[HW + m] = cos(phi);
}

// ---------------------------------------------------------------------------
// departure-point trig + bicubic sample. Hybrid precision: fp32 fast path for
// low-amplification pixels; bit-identical-to-round-2 fp64 path otherwise.
// ---------------------------------------------------------------------------
__global__ __launch_bounds__(256)
void semilag(const float* __restrict__ vel,     // [2*Cc][HW] batch base
             const float* __restrict__ hid,     // [Cc][HW] batch base
             const double* __restrict__ sphid,  // [2][HW] sin/cos(lat)
             const float* __restrict__ lng,     // [HW]
             const float* __restrict__ dtp,
             float* __restrict__ out)           // [Cc][HW] batch base
{
    int idx = blockIdx.x * 256 + threadIdx.x;
    if (idx >= Cc * HW) return;
    int c = idx / HW;
    int m = idx - c * HW;

    const double TWO_PI = 6.2831853071795864769252867665590;
    const double PI_D   = 3.1415926535897932384626433832795;
    const float  PI2F   = 6.28318530717958647692f;

    float uf = vel[idx];
    float vf = vel[Cc * HW + idx];
    float dtf = dtp[0];
    double sphi_d = sphid[m], cphi_d = sphid[HW + m];
    float lam_f = lng[m];

    // ---- fp32 gate evaluation ----
    float lonp_f = -uf * dtf, latp_f = -vf * dtf;
    float slp_f = sinf(latp_f), clp_f = cosf(latp_f);
    float slo_f = sinf(lonp_f), clo_f = cosf(lonp_f);
    float sphi_f = (float)sphi_d, cphi_f = (float)cphi_d;
    float sinlat_f = slp_f * cphi_f + clp_f * clo_f * sphi_f;
    float num_f = clp_f * slo_f;
    float den_f = clp_f * clo_f * cphi_f - slp_f * sphi_f;
    float r2_f  = num_f * num_f + den_f * den_f;

    float lon_w = lam_f + atan2f(num_f, den_f) + PI2F;
    lon_w = lon_w - floorf(lon_w / PI2F) * PI2F;
    float seam = fminf(lon_w, PI2F - lon_w);

    bool fast = (cphi_f > 0.2f) & (r2_f > 0.01f) & (fabsf(sinlat_f) < 0.98f) & (seam > 1e-4f);

    double ixd, iyd;
    if (fast) {
        float sl = fminf(fmaxf(sinlat_f, -1.f + 1e-7f), 1.f - 1e-7f);
        float lat_dep = asinf(sl);
        float gx = (lon_w / PI2F * 2.f - 1.f) * (480.f / 482.f);
        float gy = (lat_dep / 3.14159265358979323846f * 2.f - 1.f) * (240.f / 242.f);
        ixd = (double)fminf(fmaxf((gx + 1.f) * 0.5f * 481.f, 0.f), 481.f);
        iyd = (double)fminf(fmaxf((gy + 1.f) * 0.5f * 241.f, 0.f), 241.f);
    } else {
        // ---- fp64 path: IDENTICAL arithmetic to round 2 ----
        double dt = (double)dtf;
        double u = (double)uf;
        double v = (double)vf;
        double lonp = -u * dt, latp = -v * dt;
        double slp, clp, slo, clo;
        sincos_small(latp, &slp, &clp);
        sincos_small(lonp, &slo, &clo);
        double sphi = sphi_d, cphi = cphi_d;

        double sinlat = slp * cphi + clp * clo * sphi;
        sinlat = fmin(fmax(sinlat, -1.0 + 1e-7), 1.0 - 1e-7);
        double lat_dep = asin(sinlat);

        double num = clp * slo;
        double den = clp * clo * cphi - slp * sphi;
        double lon_dep = (double)lam_f + atan2(num, den);
        double xr = lon_dep + TWO_PI;
        xr = xr - floor(xr / TWO_PI) * TWO_PI;

        double gx = (xr / TWO_PI * 2.0 - 1.0) * (480.0 / 482.0);
        double gy = (lat_dep / PI_D * 2.0 - 1.0) * (240.0 / 242.0);

        ixd = fmin(fmax((gx + 1.0) * 0.5 * 481.0, 0.0), 481.0);
        iyd = fmin(fmax((gy + 1.0) * 0.5 * 241.0, 0.0), 241.0);
    }

    double x0d = floor(ixd), y0d = floor(iyd);
    float fx = (float)(ixd - x0d), fy = (float)(iyd - y0d);
    int x0 = (int)x0d, y0 = (int)y0d;

    const float a = -0.75f;
    float wx[4], wy[4];
    {
        float t = fx;
        float t1 = 1.f + t, t2 = 2.f - t, s1 = 1.f - t;
        wx[0] = ((a * t1 - 5.f * a) * t1 + 8.f * a) * t1 - 4.f * a;
        wx[1] = ((a + 2.f) * t - (a + 3.f)) * t * t + 1.f;
        wx[2] = ((a + 2.f) * s1 - (a + 3.f)) * s1 * s1 + 1.f;
        wx[3] = ((a * t2 - 5.f * a) * t2 + 8.f * a) * t2 - 4.f * a;
        t = fy;
        t1 = 1.f + t; t2 = 2.f - t; s1 = 1.f - t;
        wy[0] = ((a * t1 - 5.f * a) * t1 + 8.f * a) * t1 - 4.f * a;
        wy[1] = ((a + 2.f) * t - (a + 3.f)) * t * t + 1.f;
        wy[2] = ((a + 2.f) * s1 - (a + 3.f)) * s1 * s1 + 1.f;
        wy[3] = ((a * t2 - 5.f * a) * t2 + 8.f * a) * t2 - 4.f * a;
    }

    const float* plane = hid + (size_t)c * HW;
    float accv = 0.f;
    #pragma unroll
    for (int i = 0; i < 4; i++) {
        int yi = min(max(y0 + i - 1, 0), 241);
        float row = 0.f;
        #pragma unroll
        for (int j = 0; j < 4; j++) {
            int xj = min(max(x0 + j - 1, 0), 481);
            row = fmaf(wx[j], padfetch(plane, yi, xj), row);
        }
        accv = fmaf(wy[i], row, accv);
    }
    out[idx] = accv;
}

// ---------------------------------------------------------------------------
extern "C" void kernel_launch(void* const* d_in, const int* in_sizes, int n_in,
                              void* d_out, int out_size, void* d_ws, size_t ws_size,
                              hipStream_t stream)
{
    const float* hidden = (const float*)d_in[0];
    const float* latg   = (const float*)d_in[1];
    const float* lng    = (const float*)d_in[2];
    const float* w1     = (const float*)d_in[3];
    const float* b1     = (const float*)d_in[4];
    const float* g      = (const float*)d_in[5];
    const float* lb     = (const float*)d_in[6];
    const float* w2     = (const float*)d_in[7];
    const float* b2     = (const float*)d_in[8];
    const float* dt     = (const float*)d_in[9];
    float* out = (float*)d_out;

    // ws layout (floats): stats[4] | part[2880] | wT1 | wT2 | y1[C*HW] | vel[2C*HW]
    float* ws    = (float*)d_ws;
    float* stats = ws;
    float* part  = ws + 4;
    float* wT1   = part + 2 * NB_RED;
    float* wT2   = wT1 + Kk * Cc;
    float* y1    = wT2 + Kk * 2 * Cc;
    float* vel   = y1 + (size_t)Cc * HW;
    double* dbuf = (double*)y1;   // y1 region reused after conv2 (8B-aligned)

    transpose_w<<<(Cc * Kk + 255) / 256, 256, 0, stream>>>(w1, wT1, Cc);
    transpose_w<<<(2 * Cc * Kk + 255) / 256, 256, 0, stream>>>(w2, wT2, 2 * Cc);

    for (int b = 0; b < 2; b++) {
        const float* hb = hidden + (size_t)b * Cc * HW;
        conv_gemm<<<dim3(HW / 128, 1), 256, 0, stream>>>(hb, wT1, b1, y1, Cc);
        reduce_stats<<<NB_RED, 256, 0, stream>>>(y1, part);
        finalize_stats<<<1, 256, 0, stream>>>(part, stats + 2 * b);
        norm_silu<<<(Cc * HW) / 256, 256, 0, stream>>>(y1, g, lb, stats + 2 * b);
        conv_gemm<<<dim3(HW / 128, 2), 256, 0, stream>>>(y1, wT2, b2, vel, 2 * Cc);
        pix_trig<<<(HW + 255) / 256, 256, 0, stream>>>(latg + (size_t)b * HW, dbuf);
        semilag<<<(Cc * HW) / 256, 256, 0, stream>>>(vel, hb, dbuf,
                                                     lng + (size_t)b * HW, dt,
                                                     out + (size_t)b * Cc * HW);
    }
}